// Round 4
// baseline (96.230 us; speedup 1.0000x reference)
//
#include <hip/hip_runtime.h>

#define XD 192
#define YD 192
#define CCH 3
#define IMG 224

// ---- ws layout (float offsets) ----
#define OFF_PAD 0
#define PADW 320                        // act row padded: col = y + 64
#define N_PAD (CCH*XD*PADW)             // 184320
#define OFF_KI (OFF_PAD + N_PAD)
#define KI_LD 96                        // 94 cols + 2 zero pad
#define N_KI (94*KI_LD)
#define OFF_KE (OFF_KI + N_KI)
#define KE_LD 40                        // 38 cols + 2 zero pad
#define N_KE (38*KE_LD)

#define N_OUT (CCH*XD*YD)               // 110592

#define QSPLIT 8
#define NCONV 576                       // 24 x-tiles * 3 ch * 8 q-phases
#define NAFF 9216                       // 36864 pixels / 4 waves per block

// Prep: zero the output, build padded activation rows and masked,
// gamma-prescaled lateral kernels in ws.
__global__ __launch_bounds__(256) void k_prep(
    const float* __restrict__ exw, const float* __restrict__ exm,
    const float* __restrict__ inw, const float* __restrict__ inm,
    const float* __restrict__ oldact, float* __restrict__ ws,
    float* __restrict__ out)
{
    const int TOT = N_OUT + N_PAD + N_KI + N_KE;
    for (int idx = blockIdx.x * 256 + threadIdx.x; idx < TOT; idx += gridDim.x * 256) {
        if (idx < N_OUT) {
            out[idx] = 0.f;
        } else if (idx < N_OUT + N_PAD) {
            const int k = idx - N_OUT;
            const int col = k % PADW;
            const int rem = k / PADW;
            float v = 0.f;
            if (col >= 64 && col < 64 + YD)
                v = oldact[rem * YD + (col - 64)];
            ws[OFF_PAD + k] = v;
        } else if (idx < N_OUT + N_PAD + N_KI) {
            const int k = idx - N_OUT - N_PAD;
            const int i = k / KI_LD, j = k % KI_LD;
            ws[OFF_KI + k] = (j < 94) ? (-0.9f * inw[i * 94 + j] * inm[i * 94 + j]) : 0.f;
        } else {
            const int k = idx - N_OUT - N_PAD - N_KI;
            const int i = k / KE_LD, j = k % KE_LD;
            ws[OFF_KE + k] = (j < 38) ? (0.9f * exw[i * 38 + j] * exm[i * 38 + j]) : 0.f;
        }
    }
}

// Fused kernel:
//  blocks [0, NCONV): lateral conv (register sliding window over ws rows)
//  blocks [NCONV, ...): afferent, 1 wave/pixel, ALL loads batch-issued into
//    register arrays before any FMA -> ~14KB in flight per wave (MLP fix)
__global__ __launch_bounds__(256, 4) void k_fused(
    const float* __restrict__ input, const float* __restrict__ affw,
    const float* __restrict__ affm, const int* __restrict__ rfstart,
    const float* __restrict__ ws, float* __restrict__ out)
{
    const int bid = blockIdx.x;
    const int tid = threadIdx.x;

    if (bid < NCONV) {
        // ---------------- lateral conv ----------------
        const int xt = bid % 24;
        const int c  = (bid / 24) % 3;
        const int q  = bid / 72;            // 0..7
        const int yg = tid & 31;
        const int xr = tid >> 5;
        const int x  = xt * 8 + xr;
        const int y0 = yg * 6;

        float acc[6] = {0.f, 0.f, 0.f, 0.f, 0.f, 0.f};
        const float* pad = ws + OFF_PAD + (size_t)c * XD * PADW;

        // inhibitory 94x94 (pre-scaled by -0.9), pad col = y + j + 17
        for (int i = q; i < 94; i += QSPLIT) {
            const int r = x + i - 47;
            if (r < 0 || r >= XD) continue;
            const float* row = pad + r * PADW + y0 + 17;
            const float4* kw = (const float4*)(ws + OFF_KI + i * KI_LD);
            float w[9];
            #pragma unroll
            for (int k = 0; k < 9; ++k) w[k] = row[k];
            #pragma unroll
            for (int g = 0; g < 24; ++g) {
                const float4 k4 = kw[g];
                #pragma unroll
                for (int t = 0; t < 6; ++t) {
                    acc[t] += k4.x * w[0 + t];
                    acc[t] += k4.y * w[1 + t];
                    acc[t] += k4.z * w[2 + t];
                    acc[t] += k4.w * w[3 + t];
                }
                #pragma unroll
                for (int k = 0; k < 5; ++k) w[k] = w[k + 4];
                #pragma unroll
                for (int k = 5; k < 9; ++k) w[k] = row[4 * (g + 1) + k];
            }
        }

        // excitatory 38x38 (pre-scaled by +0.9), pad col = y + j + 45
        for (int i = q; i < 38; i += QSPLIT) {
            const int r = x + i - 19;
            if (r < 0 || r >= XD) continue;
            const float* row = pad + r * PADW + y0 + 45;
            const float4* kw = (const float4*)(ws + OFF_KE + i * KE_LD);
            float w[9];
            #pragma unroll
            for (int k = 0; k < 9; ++k) w[k] = row[k];
            #pragma unroll
            for (int g = 0; g < 10; ++g) {
                const float4 k4 = kw[g];
                #pragma unroll
                for (int t = 0; t < 6; ++t) {
                    acc[t] += k4.x * w[0 + t];
                    acc[t] += k4.y * w[1 + t];
                    acc[t] += k4.z * w[2 + t];
                    acc[t] += k4.w * w[3 + t];
                }
                #pragma unroll
                for (int k = 0; k < 5; ++k) w[k] = w[k + 4];
                #pragma unroll
                for (int k = 5; k < 9; ++k) w[k] = row[4 * (g + 1) + k];
            }
        }

        float* op = out + ((size_t)c * XD + x) * YD + y0;
        #pragma unroll
        for (int t = 0; t < 6; ++t) atomicAdd(&op[t], acc[t]);

    } else {
        // ---------------- afferent ----------------
        const int xy   = (bid - NCONV) * 4 + (tid >> 6);
        const int lane = tid & 63;
        const int sx = rfstart[xy * 2 + 0];
        const int sy = rfstart[xy * 2 + 1];
        const float4* W4 = (const float4*)affw + (size_t)xy * 144;
        const float4* M4 = (const float4*)affm;

        float4 wv[7], mv[7], iv[7];

        // ---- batch-issue ALL loads (no consumption in between) ----
        #pragma unroll
        for (int it = 0; it < 7; ++it) {
            const int g0 = lane + (it << 6);
            const int g  = (g0 < 432) ? g0 : 0;      // clamp tail (in-bounds)
            const int c  = (g >= 288) ? 2 : ((g >= 144) ? 1 : 0);
            const int r  = g - c * 144;
            wv[it] = W4[(size_t)c * 5308416 + r];    // 36864*144
        }
        #pragma unroll
        for (int it = 0; it < 7; ++it) {
            const int g0 = lane + (it << 6);
            const int g  = (g0 < 432) ? g0 : 0;
            const int c  = (g >= 288) ? 2 : ((g >= 144) ? 1 : 0);
            const int r  = g - c * 144;
            const int u  = (r * 2731) >> 14;         // r/6
            const int v  = (r - u * 6) << 2;
            const float* ip = input + c * (IMG * IMG) + (sx + u) * IMG + (sy + v);
            __builtin_memcpy(&iv[it], ip, sizeof(float4));
        }
        #pragma unroll
        for (int it = 0; it < 7; ++it) {
            const int g0 = lane + (it << 6);
            const int g  = (g0 < 432) ? g0 : 0;
            const int c  = (g >= 288) ? 2 : ((g >= 144) ? 1 : 0);
            const int r  = g - c * 144;
            float4 m = M4[r];
            if (g0 >= 432) { m.x = 0.f; m.y = 0.f; m.z = 0.f; m.w = 0.f; }
            mv[it] = m;
        }

        // ---- consume ----
        float acc = 0.f;
        #pragma unroll
        for (int it = 0; it < 7; ++it) {
            acc += iv[it].x * mv[it].x * wv[it].x;
            acc += iv[it].y * mv[it].y * wv[it].y;
            acc += iv[it].z * mv[it].z * wv[it].z;
            acc += iv[it].w * mv[it].w * wv[it].w;
        }
        #pragma unroll
        for (int off = 32; off > 0; off >>= 1) acc += __shfl_xor(acc, off);
        if (lane < 3) atomicAdd(out + (size_t)lane * (XD * YD) + xy, acc);
    }
}

extern "C" void kernel_launch(void* const* d_in, const int* in_sizes, int n_in,
                              void* d_out, int out_size, void* d_ws, size_t ws_size,
                              hipStream_t stream)
{
    const float* input   = (const float*)d_in[0];
    const float* affw    = (const float*)d_in[1];
    const float* exw     = (const float*)d_in[2];
    const float* inw     = (const float*)d_in[3];
    const float* affm    = (const float*)d_in[4];
    const float* exm     = (const float*)d_in[5];
    const float* inm     = (const float*)d_in[6];
    const float* oldact  = (const float*)d_in[7];
    const int*   rfstart = (const int*)d_in[8];
    float* out = (float*)d_out;
    float* ws  = (float*)d_ws;

    hipLaunchKernelGGL(k_prep, dim3(1194), dim3(256), 0, stream,
                       exw, exm, inw, inm, oldact, ws, out);

    hipLaunchKernelGGL(k_fused, dim3(NCONV + NAFF), dim3(256), 0, stream,
                       input, affw, affm, rfstart, ws, out);
}

// Round 5
// 94.770 us; speedup vs baseline: 1.0154x; 1.0154x over previous
//
#include <hip/hip_runtime.h>

#define XD 192
#define YD 192
#define CCH 3
#define IMG 224

// ---- ws layout (float offsets) ----
#define OFF_PAD 0
#define PADW 320                        // act row padded: col = y + 64
#define N_PAD (CCH*XD*PADW)             // 184320
#define OFF_KI (OFF_PAD + N_PAD)
#define KI_LD 96                        // 94 cols + 2 zero pad
#define N_KI (94*KI_LD)
#define OFF_KE (OFF_KI + N_KI)
#define KE_LD 40                        // 38 cols + 2 zero pad
#define N_KE (38*KE_LD)

#define N_OUT (CCH*XD*YD)               // 110592

#define QSPLIT 8
#define NCONV 576                       // 24 x-tiles * 3 ch * 8 q-phases
#define NAFF 9216                       // 36864 pixels / 4 waves per block

// Prep: zero the output, build padded activation rows and masked,
// gamma-prescaled lateral kernels in ws.
__global__ __launch_bounds__(256) void k_prep(
    const float* __restrict__ exw, const float* __restrict__ exm,
    const float* __restrict__ inw, const float* __restrict__ inm,
    const float* __restrict__ oldact, float* __restrict__ ws,
    float* __restrict__ out)
{
    const int TOT = N_OUT + N_PAD + N_KI + N_KE;
    for (int idx = blockIdx.x * 256 + threadIdx.x; idx < TOT; idx += gridDim.x * 256) {
        if (idx < N_OUT) {
            out[idx] = 0.f;
        } else if (idx < N_OUT + N_PAD) {
            const int k = idx - N_OUT;
            const int col = k % PADW;
            const int rem = k / PADW;
            float v = 0.f;
            if (col >= 64 && col < 64 + YD)
                v = oldact[rem * YD + (col - 64)];
            ws[OFF_PAD + k] = v;
        } else if (idx < N_OUT + N_PAD + N_KI) {
            const int k = idx - N_OUT - N_PAD;
            const int i = k / KI_LD, j = k % KI_LD;
            ws[OFF_KI + k] = (j < 94) ? (-0.9f * inw[i * 94 + j] * inm[i * 94 + j]) : 0.f;
        } else {
            const int k = idx - N_OUT - N_PAD - N_KI;
            const int i = k / KE_LD, j = k % KE_LD;
            ws[OFF_KE + k] = (j < 38) ? (0.9f * exw[i * 38 + j] * exm[i * 38 + j]) : 0.f;
        }
    }
}

// Fused kernel:
//  blocks [0, NCONV): lateral conv (register sliding window over ws rows)
//  blocks [NCONV, ...): afferent, 1 wave/pixel. All 21 loads are issued in a
//    pinned phase (sched_barrier) so they stay in flight together -> wave
//    lifetime ~1 memory latency instead of ~21.
__global__ __launch_bounds__(256, 3) void k_fused(
    const float* __restrict__ input, const float* __restrict__ affw,
    const float* __restrict__ affm, const int* __restrict__ rfstart,
    const float* __restrict__ ws, float* __restrict__ out)
{
    const int bid = blockIdx.x;
    const int tid = threadIdx.x;

    if (bid < NCONV) {
        // ---------------- lateral conv ----------------
        const int xt = bid % 24;
        const int c  = (bid / 24) % 3;
        const int q  = bid / 72;            // 0..7
        const int yg = tid & 31;
        const int xr = tid >> 5;
        const int x  = xt * 8 + xr;
        const int y0 = yg * 6;

        float acc[6] = {0.f, 0.f, 0.f, 0.f, 0.f, 0.f};
        const float* pad = ws + OFF_PAD + (size_t)c * XD * PADW;

        // inhibitory 94x94 (pre-scaled by -0.9), pad col = y + j + 17
        for (int i = q; i < 94; i += QSPLIT) {
            const int r = x + i - 47;
            if (r < 0 || r >= XD) continue;
            const float* row = pad + r * PADW + y0 + 17;
            const float4* kw = (const float4*)(ws + OFF_KI + i * KI_LD);
            float w[9];
            #pragma unroll
            for (int k = 0; k < 9; ++k) w[k] = row[k];
            #pragma unroll
            for (int g = 0; g < 24; ++g) {
                const float4 k4 = kw[g];
                #pragma unroll
                for (int t = 0; t < 6; ++t) {
                    acc[t] += k4.x * w[0 + t];
                    acc[t] += k4.y * w[1 + t];
                    acc[t] += k4.z * w[2 + t];
                    acc[t] += k4.w * w[3 + t];
                }
                #pragma unroll
                for (int k = 0; k < 5; ++k) w[k] = w[k + 4];
                #pragma unroll
                for (int k = 5; k < 9; ++k) w[k] = row[4 * (g + 1) + k];
            }
        }

        // excitatory 38x38 (pre-scaled by +0.9), pad col = y + j + 45
        for (int i = q; i < 38; i += QSPLIT) {
            const int r = x + i - 19;
            if (r < 0 || r >= XD) continue;
            const float* row = pad + r * PADW + y0 + 45;
            const float4* kw = (const float4*)(ws + OFF_KE + i * KE_LD);
            float w[9];
            #pragma unroll
            for (int k = 0; k < 9; ++k) w[k] = row[k];
            #pragma unroll
            for (int g = 0; g < 10; ++g) {
                const float4 k4 = kw[g];
                #pragma unroll
                for (int t = 0; t < 6; ++t) {
                    acc[t] += k4.x * w[0 + t];
                    acc[t] += k4.y * w[1 + t];
                    acc[t] += k4.z * w[2 + t];
                    acc[t] += k4.w * w[3 + t];
                }
                #pragma unroll
                for (int k = 0; k < 5; ++k) w[k] = w[k + 4];
                #pragma unroll
                for (int k = 5; k < 9; ++k) w[k] = row[4 * (g + 1) + k];
            }
        }

        float* op = out + ((size_t)c * XD + x) * YD + y0;
        #pragma unroll
        for (int t = 0; t < 6; ++t) atomicAdd(&op[t], acc[t]);

    } else {
        // ---------------- afferent ----------------
        const int wv_id = __builtin_amdgcn_readfirstlane(tid >> 6);  // SGPR
        const int xy    = (bid - NCONV) * 4 + wv_id;
        const int lane  = tid & 63;
        const int sx = rfstart[xy * 2 + 0];      // scalar loads (uniform idx)
        const int sy = rfstart[xy * 2 + 1];
        const float4* W4 = (const float4*)affw + (size_t)xy * 144;
        const float4* M4 = (const float4*)affm;

        float4 wv[7], mv[7], iv[7];

        // ---- phase 1: issue ALL loads, pinned by sched_barrier ----
        #pragma unroll
        for (int it = 0; it < 7; ++it) {
            const int g0 = lane + (it << 6);
            const int g  = (g0 < 432) ? g0 : 0;      // clamp tail (in-bounds)
            const int c  = (g >= 288) ? 2 : ((g >= 144) ? 1 : 0);
            const int r  = g - c * 144;
            wv[it] = W4[(size_t)c * 5308416 + r];    // 36864*144
        }
        #pragma unroll
        for (int it = 0; it < 7; ++it) {
            const int g0 = lane + (it << 6);
            const int g  = (g0 < 432) ? g0 : 0;
            const int c  = (g >= 288) ? 2 : ((g >= 144) ? 1 : 0);
            const int r  = g - c * 144;
            const int u  = (r * 2731) >> 14;         // r/6
            const int v  = (r - u * 6) << 2;
            const float* ip = input + c * (IMG * IMG) + (sx + u) * IMG + (sy + v);
            __builtin_memcpy(&iv[it], ip, sizeof(float4));
        }
        #pragma unroll
        for (int it = 0; it < 7; ++it) {
            const int g0 = lane + (it << 6);
            const int g  = (g0 < 432) ? g0 : 0;
            const int c  = (g >= 288) ? 2 : ((g >= 144) ? 1 : 0);
            const int r  = g - c * 144;
            mv[it] = M4[r];
        }
        __builtin_amdgcn_sched_barrier(0);   // loads may NOT sink past here

        // ---- phase 2: consume ----
        float acc = 0.f;
        #pragma unroll
        for (int it = 0; it < 7; ++it) {
            const int g0 = lane + (it << 6);
            const float z = (g0 < 432) ? 1.f : 0.f;  // kill clamped tail
            acc += iv[it].x * (z * mv[it].x) * wv[it].x;
            acc += iv[it].y * (z * mv[it].y) * wv[it].y;
            acc += iv[it].z * (z * mv[it].z) * wv[it].z;
            acc += iv[it].w * (z * mv[it].w) * wv[it].w;
        }
        #pragma unroll
        for (int off = 32; off > 0; off >>= 1) acc += __shfl_xor(acc, off);
        if (lane < 3) atomicAdd(out + (size_t)lane * (XD * YD) + xy, acc);
    }
}

extern "C" void kernel_launch(void* const* d_in, const int* in_sizes, int n_in,
                              void* d_out, int out_size, void* d_ws, size_t ws_size,
                              hipStream_t stream)
{
    const float* input   = (const float*)d_in[0];
    const float* affw    = (const float*)d_in[1];
    const float* exw     = (const float*)d_in[2];
    const float* inw     = (const float*)d_in[3];
    const float* affm    = (const float*)d_in[4];
    const float* exm     = (const float*)d_in[5];
    const float* inm     = (const float*)d_in[6];
    const float* oldact  = (const float*)d_in[7];
    const int*   rfstart = (const int*)d_in[8];
    float* out = (float*)d_out;
    float* ws  = (float*)d_ws;

    hipLaunchKernelGGL(k_prep, dim3(1194), dim3(256), 0, stream,
                       exw, exm, inw, inm, oldact, ws, out);

    hipLaunchKernelGGL(k_fused, dim3(NCONV + NAFF), dim3(256), 0, stream,
                       input, affw, affm, rfstart, ws, out);
}